// Round 5
// baseline (191.170 us; speedup 1.0000x reference)
//
#include <hip/hip_runtime.h>

#define NS 5      // symbols
#define NW 33     // subcarriers
#define NA 16     // antennas
#define SW 165    // NS*NW
#define BUFS 99   // per-matrix LDS buffer (f2): x-chunk (55), then T2 (99)
#define CW 11     // w-columns per chunk (3 chunks of 11)
#define CH (CW*NS)     // 55 f2 per matrix per chunk
#define CE (CH*MPW)    // 275 f2 per wave per chunk
#define MPW 5     // matrices per wave
#define GM 20     // matrices per block
#define TPM 11    // threads per matrix
#define CPT 3     // columns per thread
#define THREADS 256

// R14: fix R13's spill. launch_bounds(256,6) caps regalloc at ~84 VGPR; R13's
// r1[7] (14 VGPR) held across 510 pk_fmas overflowed that -> scratch spill
// (the +18/+16 MB FETCH/WRITE delta). Now 3 chunks of 11 w-cols, 5-reg stage
// buffer, load(c+1) pipelined over compute(c): peak live ~78 VGPR, no spill.
// Chunk overwrite of wave-private LDS region is order-safe (aliasing ds ops,
// per-wave in-order DS). Kept: 99-f2 buffer/6 blocks (R13), pk_fma (R11),
// wave-autonomy (R10), LDS-coalesced staging (R12 lesson).
typedef float f2 __attribute__((ext_vector_type(2)));

// z += x * f (complex).  inst1: (zr,zi) += (xr,xi)*(fr,fr)
//                        inst2: (zr,zi) += (-xi,xr)*(fi,fi)
__device__ __forceinline__ void cmac(f2& z, f2 x, f2 f) {
    asm("v_pk_fma_f32 %0, %1, %2, %0 op_sel:[0,0,0] op_sel_hi:[1,0,1]"
        : "+v"(z) : "v"(x), "v"(f));
    asm("v_pk_fma_f32 %0, %1, %2, %0 op_sel:[1,1,0] op_sel_hi:[0,1,1] neg_lo:[1,0,0]"
        : "+v"(z) : "v"(x), "v"(f));
}

// z += conj(f) * P, P real pair Pp=(P,P): lo zr+=f.x*P, hi zi+=-f.y*P
__device__ __forceinline__ void cmacr(f2& z, f2 f, f2 Pp) {
    asm("v_pk_fma_f32 %0, %1, %2, %0 op_sel:[0,0,0] op_sel_hi:[1,1,1] neg_hi:[1,0,0]"
        : "+v"(z) : "v"(f), "v"(Pp));
}

// plain packed: z += a*b elementwise
__device__ __forceinline__ void pkfma(f2& z, f2 a, f2 b) {
    asm("v_pk_fma_f32 %0, %1, %2, %0 op_sel:[0,0,0] op_sel_hi:[1,1,1]"
        : "+v"(z) : "v"(a), "v"(b));
}

// Load one 11-col x-chunk into 5 regs/lane (issued ahead of its compute phase).
#define STAGE_LOAD(R, W0)                                                  \
    _Pragma("unroll")                                                      \
    for (int i = 0; i < 5; ++i) {                                          \
        const int e = lane + i * 64;                                       \
        f2 v = (f2){0.f, 0.f};                                             \
        if (e < CE) {                                                      \
            const int gq = e / CH, rq = e - gq * CH;                       \
            const int tq = rq / CW, wq = rq - tq * CW;                     \
            const int Mq = Mw + gq;                                        \
            if (Mq < NM) {                                                 \
                const int nq = Mq >> 4, aq = Mq & 15;                      \
                const int go = ((nq * NS + tq) * NA + aq) * NW + (W0) + wq;\
                v = (f2){x_real[go], x_imag[go]};                          \
            }                                                              \
        }                                                                  \
        R[i] = v;                                                          \
    }

// Write a register-staged chunk into the wave-private LDS region, layout
// [w_local*NS + t] per matrix (chunk-local w).
#define STAGE_WRITE(R)                                                     \
    _Pragma("unroll")                                                      \
    for (int i = 0; i < 5; ++i) {                                          \
        const int e = lane + i * 64;                                       \
        if (e < CE) {                                                      \
            const int gq = e / CH, rq = e - gq * CH;                       \
            const int tq = rq / CW, wq = rq - tq * CW;                     \
            wbuf[gq * BUFS + wq * NS + tq] = R[i];                         \
        }                                                                  \
    }

// One 11-col fused A+B chunk: V[t][k] += sum_w x[t][w] * Fsub[W0+w][c0+k]
#define COMPUTE_CHUNK(W0)                                                  \
    if (act) {                                                             \
        const f2* bp = wbuf + gg * BUFS;                                   \
        _Pragma("unroll 3")                                                \
        for (int w = 0; w < CW; ++w) {                                     \
            f2 xc[NS];                                                     \
            _Pragma("unroll")                                              \
            for (int t = 0; t < NS; ++t) xc[t] = bp[w * NS + t];           \
            f2 fv[CPT];                                                    \
            _Pragma("unroll")                                              \
            for (int k = 0; k < CPT; ++k)                                  \
                fv[k] = sFsub[((W0) + w) * NW + c0 + k];                   \
            _Pragma("unroll")                                              \
            for (int t = 0; t < NS; ++t)                                   \
                _Pragma("unroll")                                          \
                for (int k = 0; k < CPT; ++k)                              \
                    cmac(V[t][k], xc[t], fv[k]);                           \
        }                                                                  \
    }

__global__ __launch_bounds__(THREADS, 6) void autocorr_kernel(
    const float* __restrict__ x_real, const float* __restrict__ x_imag,
    const float* __restrict__ Fsym_re, const float* __restrict__ Fsym_im,
    const float* __restrict__ Fsub_re, const float* __restrict__ Fsub_im,
    float* __restrict__ out, int NM, int write_complex)
{
    __shared__ f2 sFsym[NS * NS];     // [s][t]
    __shared__ f2 sFsub[NW * NW];     // [w][v] row-major (symmetric)
    __shared__ f2 buf[GM * BUFS];     // per-matrix 99: x chunk (55), then T2

    const int tid = threadIdx.x;
    const int wave = tid >> 6;
    const int lane = tid & 63;
    const int Mw = blockIdx.x * GM + wave * MPW;
    f2* const wbuf = &buf[wave * MPW * BUFS];

    // ---- F staging (cooperative) ----
    for (int i = tid; i < NW * NW; i += THREADS)
        sFsub[i] = (f2){Fsub_re[i], Fsub_im[i]};
    if (tid < NS * NS) sFsym[tid] = (f2){Fsym_re[tid], Fsym_im[tid]};

    // ---- chunk0: global->reg (overlaps F staging), reg->LDS ----
    f2 rA[5], rB[5];
    STAGE_LOAD(rA, 0);
    STAGE_WRITE(rA);
    __syncthreads();   // the ONLY barrier: F tables visible (c0 is wave-private)

    // ---- chunk1 loads issue now; latency hides under chunk0 compute ----
    STAGE_LOAD(rB, CW);

    const int g = lane / TPM;                 // 0..4 active, 5 for idle lanes
    const int j = lane - g * TPM;
    const bool act = (lane < MPW * TPM);      // 55 of 64 lanes compute
    const int gg = act ? g : 0;
    const int M = Mw + gg;
    const int Ms = (M < NM) ? M : 0;
    const int n = Ms >> 4, a = Ms & 15;
    const int c0 = 3 * j;

    f2 V[NS][CPT];
#pragma unroll
    for (int t = 0; t < NS; ++t)
#pragma unroll
        for (int k = 0; k < CPT; ++k) V[t][k] = (f2){0.f, 0.f};

    // ---- pipelined chunks: compute(c) overlaps load(c+1) ----
    COMPUTE_CHUNK(0);
    STAGE_WRITE(rB);                 // chunk1 -> LDS (vmcnt auto; aliases c0 reads)
    STAGE_LOAD(rA, 2 * CW);          // chunk2 loads issue; hide under chunk1 compute
    asm volatile("s_waitcnt lgkmcnt(0)" ::: "memory");
    COMPUTE_CHUNK(CW);
    STAGE_WRITE(rA);                 // chunk2 -> LDS
    asm volatile("s_waitcnt lgkmcnt(0)" ::: "memory");
    COMPUTE_CHUNK(2 * CW);

    // ---- X = F_sym*V; P = |X|^2; Stage D (Hermitian p<3) -> T2 ----
    f2 T2[3][CPT];
#pragma unroll
    for (int p = 0; p < 3; ++p)
#pragma unroll
        for (int k = 0; k < CPT; ++k) T2[p][k] = (f2){0.f, 0.f};
    if (act) {
#pragma unroll
        for (int s = 0; s < NS; ++s) {
            f2 X[CPT];
#pragma unroll
            for (int k = 0; k < CPT; ++k) X[k] = (f2){0.f, 0.f};
#pragma unroll
            for (int t = 0; t < NS; ++t) {
                f2 f = sFsym[s * NS + t];
#pragma unroll
                for (int k = 0; k < CPT; ++k)
                    cmac(X[k], f, V[t][k]);
            }
#pragma unroll
            for (int k = 0; k < CPT; ++k) {
                const float Pv = X[k].x * X[k].x + X[k].y * X[k].y;
                const f2 Pp = (f2){Pv, Pv};
#pragma unroll
                for (int p = 0; p < 3; ++p)
                    cmacr(T2[p][k], sFsym[s * NS + p], Pp);
            }
        }
        // T2 col-major into the same wave-private region (after all x reads).
        f2* const wb = wbuf + gg * BUFS;
#pragma unroll
        for (int k = 0; k < CPT; ++k)
#pragma unroll
            for (int p = 0; p < 3; ++p)
                wb[(c0 + k) * 3 + p] = T2[p][k];
    }
    asm volatile("s_waitcnt lgkmcnt(0)" ::: "memory");

    // ---- Stage E: Y[p][q] = sum_v T2[p][v]*conj(Fsub[q][v]), q = c0+k ----
    if (act) {
        const f2* bp = wbuf + gg * BUFS;
        if (!write_complex) {
            f2 Ypk[3][CPT];
#pragma unroll
            for (int p = 0; p < 3; ++p)
#pragma unroll
                for (int k = 0; k < CPT; ++k) Ypk[p][k] = (f2){0.f, 0.f};
#pragma unroll 3
            for (int v = 0; v < NW; ++v) {
                f2 tc[3];
#pragma unroll
                for (int p = 0; p < 3; ++p) tc[p] = bp[v * 3 + p];
                f2 fw[CPT];
#pragma unroll
                for (int k = 0; k < CPT; ++k) fw[k] = sFsub[(c0 + k) * NW + v];
#pragma unroll
                for (int p = 0; p < 3; ++p)
#pragma unroll
                    for (int k = 0; k < CPT; ++k)
                        pkfma(Ypk[p][k], tc[p], fw[k]);   // Re fold at end
            }
            if (M < NM) {
                int obase = ((n * NS) * NA + a) * NW;
#pragma unroll
                for (int p = 0; p < 3; ++p) {
                    const int pp = (NS - p) % NS;   // 0,4,3
#pragma unroll
                    for (int k = 0; k < CPT; ++k) {
                        const int q = c0 + k;
                        const int qq = (NW - q) % NW;
                        const float Yr = Ypk[p][k].x + Ypk[p][k].y;
                        out[obase + p * (NA * NW) + q] = Yr;
                        out[obase + pp * (NA * NW) + qq] = Yr;
                    }
                }
            }
        } else {
            // Fallback: full complex output (not expected on this harness).
            f2 Y[3][CPT];
#pragma unroll
            for (int p = 0; p < 3; ++p)
#pragma unroll
                for (int k = 0; k < CPT; ++k) Y[p][k] = (f2){0.f, 0.f};
            for (int v = 0; v < NW; ++v) {
                f2 tc[3];
#pragma unroll
                for (int p = 0; p < 3; ++p) tc[p] = bp[v * 3 + p];
                f2 fw[CPT];
#pragma unroll
                for (int k = 0; k < CPT; ++k) fw[k] = sFsub[(c0 + k) * NW + v];
#pragma unroll
                for (int p = 0; p < 3; ++p)
#pragma unroll
                    for (int k = 0; k < CPT; ++k) {
                        Y[p][k].x = fmaf(tc[p].x, fw[k].x, Y[p][k].x);
                        Y[p][k].x = fmaf(tc[p].y, fw[k].y, Y[p][k].x);
                        Y[p][k].y = fmaf(tc[p].y, fw[k].x, Y[p][k].y);
                        Y[p][k].y = fmaf(-tc[p].x, fw[k].y, Y[p][k].y);
                    }
            }
            if (M < NM) {
#pragma unroll
                for (int p = 0; p < 3; ++p) {
                    const int pp = (NS - p) % NS;
#pragma unroll
                    for (int k = 0; k < CPT; ++k) {
                        const int q = c0 + k;
                        const int qq = (NW - q) % NW;
                        ((float2*)out)[((n * NS + p) * NA + a) * NW + q] =
                            make_float2(Y[p][k].x, Y[p][k].y);
                        ((float2*)out)[((n * NS + pp) * NA + a) * NW + qq] =
                            make_float2(Y[p][k].x, -Y[p][k].y);
                    }
                }
            }
        }
    }
}

extern "C" void kernel_launch(void* const* d_in, const int* in_sizes, int n_in,
                              void* d_out, int out_size, void* d_ws, size_t ws_size,
                              hipStream_t stream) {
    const float* x_real  = (const float*)d_in[0];
    const float* x_imag  = (const float*)d_in[1];
    const float* Fsym_re = (const float*)d_in[2];
    const float* Fsym_im = (const float*)d_in[3];
    const float* Fsub_re = (const float*)d_in[4];
    const float* Fsub_im = (const float*)d_in[5];

    const int NM = in_sizes[0] / SW;
    const long long n_cplx = (long long)in_sizes[0];
    const int write_complex = ((long long)out_size >= 2 * n_cplx) ? 1 : 0;

    const int blocks = (NM + GM - 1) / GM;

    autocorr_kernel<<<blocks, THREADS, 0, stream>>>(
        x_real, x_imag, Fsym_re, Fsym_im, Fsub_re, Fsub_im,
        (float*)d_out, NM, write_complex);
}

// Round 6
// 179.568 us; speedup vs baseline: 1.0646x; 1.0646x over previous
//
#include <hip/hip_runtime.h>

#define NS 5      // symbols
#define NW 33     // subcarriers
#define NA 16     // antennas
#define SW 165    // NS*NW
#define BUFS 99   // per-matrix LDS buffer (f2): x-chunk (<=95), then T2 (99)
#define MPW 5     // matrices per wave
#define GM 20     // matrices per block
#define TPM 11    // threads per matrix
#define CPT 3     // columns per thread
#define THREADS 256

#define CW0 19            // chunk0 w-columns
#define CH0 (CW0*NS)      // 95 f2 per matrix
#define CE0 (CH0*MPW)     // 475 f2 per wave
#define IT0 8             // ceil(475/64)
#define CW1 14            // chunk1 w-columns
#define CH1 (CW1*NS)      // 70 f2 per matrix
#define CE1 (CH1*MPW)     // 350 f2 per wave
#define IT1 6             // ceil(350/64)

// R15: 6-block LDS layout kept (R13 win: occupancy 36->52%), register
// prefetch DELETED (R13/R14 lesson: at launch_bounds(256,6) the budget is
// effectively 64 VGPR -- m69 occupancy quantum: 24 waves/CU requires <=64 --
// and any buffer held across compute spills to scratch: R14's +75/+44 MB
// FETCH/WRITE). Staging is now load-all->write-all with transient regs, dead
// before compute; 2 chunks (19+14). TLP at 24 waves covers the one exposed
// stage (T14 regime: null at high occupancy). Kept: pk_fma (R11),
// wave-autonomy (R10), LDS-coalesced staging (R12 lesson).
typedef float f2 __attribute__((ext_vector_type(2)));

// z += x * f (complex).  inst1: (zr,zi) += (xr,xi)*(fr,fr)
//                        inst2: (zr,zi) += (-xi,xr)*(fi,fi)
__device__ __forceinline__ void cmac(f2& z, f2 x, f2 f) {
    asm("v_pk_fma_f32 %0, %1, %2, %0 op_sel:[0,0,0] op_sel_hi:[1,0,1]"
        : "+v"(z) : "v"(x), "v"(f));
    asm("v_pk_fma_f32 %0, %1, %2, %0 op_sel:[1,1,0] op_sel_hi:[0,1,1] neg_lo:[1,0,0]"
        : "+v"(z) : "v"(x), "v"(f));
}

// z += conj(f) * P, P real pair Pp=(P,P): lo zr+=f.x*P, hi zi+=-f.y*P
__device__ __forceinline__ void cmacr(f2& z, f2 f, f2 Pp) {
    asm("v_pk_fma_f32 %0, %1, %2, %0 op_sel:[0,0,0] op_sel_hi:[1,1,1] neg_hi:[1,0,0]"
        : "+v"(z) : "v"(f), "v"(Pp));
}

// plain packed: z += a*b elementwise
__device__ __forceinline__ void pkfma(f2& z, f2 a, f2 b) {
    asm("v_pk_fma_f32 %0, %1, %2, %0 op_sel:[0,0,0] op_sel_hi:[1,1,1]"
        : "+v"(z) : "v"(a), "v"(b));
}

// Stage one x-chunk: issue ALL loads, then ALL ds_writes (compiler inserts
// vmcnt). rr[] is transient -- dead before any compute uses the LDS data.
#define STAGE(CW, CH, CE, NIT, W0)                                         \
    {                                                                      \
        f2 rr[NIT];                                                        \
        _Pragma("unroll")                                                  \
        for (int i = 0; i < NIT; ++i) {                                    \
            const int e = lane + i * 64;                                   \
            f2 v = (f2){0.f, 0.f};                                         \
            if (e < (CE)) {                                                \
                const int gq = e / (CH), rq = e - gq * (CH);               \
                const int tq = rq / (CW), wq = rq - tq * (CW);             \
                const int Mq = Mw + gq;                                    \
                if (Mq < NM) {                                             \
                    const int nq = Mq >> 4, aq = Mq & 15;                  \
                    const int go = ((nq * NS + tq) * NA + aq) * NW + (W0) + wq; \
                    v = (f2){x_real[go], x_imag[go]};                      \
                }                                                          \
            }                                                              \
            rr[i] = v;                                                     \
        }                                                                  \
        _Pragma("unroll")                                                  \
        for (int i = 0; i < NIT; ++i) {                                    \
            const int e = lane + i * 64;                                   \
            if (e < (CE)) {                                                \
                const int gq = e / (CH), rq = e - gq * (CH);               \
                const int tq = rq / (CW), wq = rq - tq * (CW);             \
                wbuf[gq * BUFS + wq * NS + tq] = rr[i];                    \
            }                                                              \
        }                                                                  \
    }

// One fused A+B chunk: V[t][k] += sum_{w<CW} x[t][w] * Fsub[W0+w][c0+k]
#define COMPUTE_CHUNK(CW, W0)                                              \
    if (act) {                                                             \
        const f2* bp = wbuf + gg * BUFS;                                   \
        _Pragma("unroll 3")                                                \
        for (int w = 0; w < (CW); ++w) {                                   \
            f2 xc[NS];                                                     \
            _Pragma("unroll")                                              \
            for (int t = 0; t < NS; ++t) xc[t] = bp[w * NS + t];           \
            f2 fv[CPT];                                                    \
            _Pragma("unroll")                                              \
            for (int k = 0; k < CPT; ++k)                                  \
                fv[k] = sFsub[((W0) + w) * NW + c0 + k];                   \
            _Pragma("unroll")                                              \
            for (int t = 0; t < NS; ++t)                                   \
                _Pragma("unroll")                                          \
                for (int k = 0; k < CPT; ++k)                              \
                    cmac(V[t][k], xc[t], fv[k]);                           \
        }                                                                  \
    }

__global__ __launch_bounds__(THREADS, 6) void autocorr_kernel(
    const float* __restrict__ x_real, const float* __restrict__ x_imag,
    const float* __restrict__ Fsym_re, const float* __restrict__ Fsym_im,
    const float* __restrict__ Fsub_re, const float* __restrict__ Fsub_im,
    float* __restrict__ out, int NM, int write_complex)
{
    __shared__ f2 sFsym[NS * NS];     // [s][t]
    __shared__ f2 sFsub[NW * NW];     // [w][v] row-major (symmetric)
    __shared__ f2 buf[GM * BUFS];     // per-matrix 99: x chunk, then T2

    const int tid = threadIdx.x;
    const int wave = tid >> 6;
    const int lane = tid & 63;
    const int Mw = blockIdx.x * GM + wave * MPW;
    f2* const wbuf = &buf[wave * MPW * BUFS];

    // ---- F staging (cooperative) ----
    for (int i = tid; i < NW * NW; i += THREADS)
        sFsub[i] = (f2){Fsub_re[i], Fsub_im[i]};
    if (tid < NS * NS) sFsym[tid] = (f2){Fsym_re[tid], Fsym_im[tid]};

    // ---- chunk0: global->reg->LDS (load latency overlaps F staging) ----
    STAGE(CW0, CH0, CE0, IT0, 0);
    __syncthreads();   // the ONLY barrier: F tables + own chunk0 drained

    const int g = lane / TPM;                 // 0..4 active, 5 for idle lanes
    const int j = lane - g * TPM;
    const bool act = (lane < MPW * TPM);      // 55 of 64 lanes compute
    const int gg = act ? g : 0;
    const int M = Mw + gg;
    const int c0 = 3 * j;

    f2 V[NS][CPT];
#pragma unroll
    for (int t = 0; t < NS; ++t)
#pragma unroll
        for (int k = 0; k < CPT; ++k) V[t][k] = (f2){0.f, 0.f};

    COMPUTE_CHUNK(CW0, 0);

    // ---- chunk1: staged only now (no regs held across compute; 24-wave TLP
    //      covers the exposed load latency). Overwrites chunk0's region:
    //      safe by per-wave in-order DS. ----
    STAGE(CW1, CH1, CE1, IT1, CW0);
    asm volatile("s_waitcnt lgkmcnt(0)" ::: "memory");

    COMPUTE_CHUNK(CW1, CW0);

    // ---- X = F_sym*V; P = |X|^2; Stage D (Hermitian p<3) -> T2 ----
    f2 T2[3][CPT];
#pragma unroll
    for (int p = 0; p < 3; ++p)
#pragma unroll
        for (int k = 0; k < CPT; ++k) T2[p][k] = (f2){0.f, 0.f};
    if (act) {
#pragma unroll
        for (int s = 0; s < NS; ++s) {
            f2 X[CPT];
#pragma unroll
            for (int k = 0; k < CPT; ++k) X[k] = (f2){0.f, 0.f};
#pragma unroll
            for (int t = 0; t < NS; ++t) {
                f2 f = sFsym[s * NS + t];
#pragma unroll
                for (int k = 0; k < CPT; ++k)
                    cmac(X[k], f, V[t][k]);
            }
#pragma unroll
            for (int k = 0; k < CPT; ++k) {
                const float Pv = X[k].x * X[k].x + X[k].y * X[k].y;
                const f2 Pp = (f2){Pv, Pv};
#pragma unroll
                for (int p = 0; p < 3; ++p)
                    cmacr(T2[p][k], sFsym[s * NS + p], Pp);
            }
        }
        // T2 col-major into the same wave-private region (after all x reads).
        f2* const wb = wbuf + gg * BUFS;
#pragma unroll
        for (int k = 0; k < CPT; ++k)
#pragma unroll
            for (int p = 0; p < 3; ++p)
                wb[(c0 + k) * 3 + p] = T2[p][k];
    }
    asm volatile("s_waitcnt lgkmcnt(0)" ::: "memory");

    // ---- Stage E: Y[p][q] = sum_v T2[p][v]*conj(Fsub[q][v]), q = c0+k ----
    if (act) {
        const f2* bp = wbuf + gg * BUFS;
        if (!write_complex) {
            f2 Ypk[3][CPT];
#pragma unroll
            for (int p = 0; p < 3; ++p)
#pragma unroll
                for (int k = 0; k < CPT; ++k) Ypk[p][k] = (f2){0.f, 0.f};
#pragma unroll 3
            for (int v = 0; v < NW; ++v) {
                f2 tc[3];
#pragma unroll
                for (int p = 0; p < 3; ++p) tc[p] = bp[v * 3 + p];
                f2 fw[CPT];
#pragma unroll
                for (int k = 0; k < CPT; ++k) fw[k] = sFsub[(c0 + k) * NW + v];
#pragma unroll
                for (int p = 0; p < 3; ++p)
#pragma unroll
                    for (int k = 0; k < CPT; ++k)
                        pkfma(Ypk[p][k], tc[p], fw[k]);   // Re fold at end
            }
            if (M < NM) {
                const int n = M >> 4, a = M & 15;   // recomputed here, not held
                const int obase = ((n * NS) * NA + a) * NW;
#pragma unroll
                for (int p = 0; p < 3; ++p) {
                    const int pp = (NS - p) % NS;   // 0,4,3
#pragma unroll
                    for (int k = 0; k < CPT; ++k) {
                        const int q = c0 + k;
                        const int qq = (NW - q) % NW;
                        const float Yr = Ypk[p][k].x + Ypk[p][k].y;
                        out[obase + p * (NA * NW) + q] = Yr;
                        out[obase + pp * (NA * NW) + qq] = Yr;
                    }
                }
            }
        } else {
            // Fallback: full complex output (not expected on this harness).
            f2 Y[3][CPT];
#pragma unroll
            for (int p = 0; p < 3; ++p)
#pragma unroll
                for (int k = 0; k < CPT; ++k) Y[p][k] = (f2){0.f, 0.f};
            for (int v = 0; v < NW; ++v) {
                f2 tc[3];
#pragma unroll
                for (int p = 0; p < 3; ++p) tc[p] = bp[v * 3 + p];
                f2 fw[CPT];
#pragma unroll
                for (int k = 0; k < CPT; ++k) fw[k] = sFsub[(c0 + k) * NW + v];
#pragma unroll
                for (int p = 0; p < 3; ++p)
#pragma unroll
                    for (int k = 0; k < CPT; ++k) {
                        Y[p][k].x = fmaf(tc[p].x, fw[k].x, Y[p][k].x);
                        Y[p][k].x = fmaf(tc[p].y, fw[k].y, Y[p][k].x);
                        Y[p][k].y = fmaf(tc[p].y, fw[k].x, Y[p][k].y);
                        Y[p][k].y = fmaf(-tc[p].x, fw[k].y, Y[p][k].y);
                    }
            }
            if (M < NM) {
                const int n = M >> 4, a = M & 15;
#pragma unroll
                for (int p = 0; p < 3; ++p) {
                    const int pp = (NS - p) % NS;
#pragma unroll
                    for (int k = 0; k < CPT; ++k) {
                        const int q = c0 + k;
                        const int qq = (NW - q) % NW;
                        ((float2*)out)[((n * NS + p) * NA + a) * NW + q] =
                            make_float2(Y[p][k].x, Y[p][k].y);
                        ((float2*)out)[((n * NS + pp) * NA + a) * NW + qq] =
                            make_float2(Y[p][k].x, -Y[p][k].y);
                    }
                }
            }
        }
    }
}

extern "C" void kernel_launch(void* const* d_in, const int* in_sizes, int n_in,
                              void* d_out, int out_size, void* d_ws, size_t ws_size,
                              hipStream_t stream) {
    const float* x_real  = (const float*)d_in[0];
    const float* x_imag  = (const float*)d_in[1];
    const float* Fsym_re = (const float*)d_in[2];
    const float* Fsym_im = (const float*)d_in[3];
    const float* Fsub_re = (const float*)d_in[4];
    const float* Fsub_im = (const float*)d_in[5];

    const int NM = in_sizes[0] / SW;
    const long long n_cplx = (long long)in_sizes[0];
    const int write_complex = ((long long)out_size >= 2 * n_cplx) ? 1 : 0;

    const int blocks = (NM + GM - 1) / GM;

    autocorr_kernel<<<blocks, THREADS, 0, stream>>>(
        x_real, x_imag, Fsym_re, Fsym_im, Fsub_re, Fsub_im,
        (float*)d_out, NM, write_complex);
}

// Round 7
// 175.569 us; speedup vs baseline: 1.0889x; 1.0228x over previous
//
#include <hip/hip_runtime.h>

#define NS 5      // symbols
#define NW 33     // subcarriers
#define NA 16     // antennas
#define SW 165    // NS*NW
#define BUFS 99   // per-matrix LDS buffer (f2): x rows chunk (<=99), then T2 (99)
#define MPW 5     // matrices per wave
#define GM 20     // matrices per block
#define TPM 11    // threads per matrix
#define CPT 3     // columns per thread
#define THREADS 256

// t-row chunks (R16): chunk0 = t{0,1,2} full rows, chunk1 = t{3,4} full rows.
// Full rows keep w and 33-w co-resident (enables conjugate pairing) and make
// global reads line-contiguous per wave (fixes R15's straddle over-fetch).
#define C0T 3
#define C0E (C0T*NW*MPW)   // 495
#define IT0 8
#define C1T 2
#define C1E (C1T*NW*MPW)   // 330
#define IT1 6

// R16: conjugate-pair FLOP cut. F[n-w][c] = conj(F[w][c]) for both DFT
// matrices, so  x[w]F + x[n-w]conj(F) = (x[w]+x[n-w])ReF + i(x[w]-x[n-w])ImF:
// 2 pk_fma + 2 pk_add per pair vs 4 pk_fma. Applied to stage A (990->655),
// stage C via in-place V transform (150->87), stage E real path (297->201).
// Kept: 6-block LDS layout (R13), transient-reg staging / no prefetch
// (R15 lesson), pk_fma (R11), wave-autonomy (R10), LDS staging (R12 lesson).
typedef float f2 __attribute__((ext_vector_type(2)));

// z += u * Re(f):  (z.x += u.x*f.lo, z.y += u.y*f.lo)
__device__ __forceinline__ void cmac_re(f2& z, f2 u, f2 f) {
    asm("v_pk_fma_f32 %0, %1, %2, %0 op_sel:[0,0,0] op_sel_hi:[1,0,1]"
        : "+v"(z) : "v"(u), "v"(f));
}
// z += i * d * Im(f):  (z.x += -d.y*f.hi, z.y += d.x*f.hi)
__device__ __forceinline__ void cmac_im(f2& z, f2 d, f2 f) {
    asm("v_pk_fma_f32 %0, %1, %2, %0 op_sel:[1,1,0] op_sel_hi:[0,1,1] neg_lo:[1,0,0]"
        : "+v"(z) : "v"(d), "v"(f));
}
// z += conj(f) * P, P real pair Pp=(P,P): lo zr+=f.x*P, hi zi+=-f.y*P
__device__ __forceinline__ void cmacr(f2& z, f2 f, f2 Pp) {
    asm("v_pk_fma_f32 %0, %1, %2, %0 op_sel:[0,0,0] op_sel_hi:[1,1,1] neg_hi:[1,0,0]"
        : "+v"(z) : "v"(f), "v"(Pp));
}
// plain packed: z += a*b elementwise
__device__ __forceinline__ void pkfma(f2& z, f2 a, f2 b) {
    asm("v_pk_fma_f32 %0, %1, %2, %0 op_sel:[0,0,0] op_sel_hi:[1,1,1]"
        : "+v"(z) : "v"(a), "v"(b));
}
// r = a + b (packed)
__device__ __forceinline__ f2 pkadd(f2 a, f2 b) {
    f2 r; asm("v_pk_add_f32 %0, %1, %2" : "=v"(r) : "v"(a), "v"(b)); return r;
}
// r = a - b (packed)
__device__ __forceinline__ f2 pksub(f2 a, f2 b) {
    f2 r; asm("v_pk_add_f32 %0, %1, %2 neg_lo:[0,1] neg_hi:[0,1]"
              : "=v"(r) : "v"(a), "v"(b)); return r;
}
// r = (a.x + b.x, a.y - b.y)
__device__ __forceinline__ f2 pkaddsub(f2 a, f2 b) {
    f2 r; asm("v_pk_add_f32 %0, %1, %2 neg_hi:[0,1]"
              : "=v"(r) : "v"(a), "v"(b)); return r;
}
// r = u * Re(f) broadcast: (u.x*f.lo, u.y*f.lo)  -- accumulator init
__device__ __forceinline__ f2 pkmul_re(f2 u, f2 f) {
    f2 r; asm("v_pk_mul_f32 %0, %1, %2 op_sel:[0,0] op_sel_hi:[1,0]"
              : "=v"(r) : "v"(u), "v"(f)); return r;
}
// r = a * b elementwise -- accumulator init
__device__ __forceinline__ f2 pkmul(f2 a, f2 b) {
    f2 r; asm("v_pk_mul_f32 %0, %1, %2" : "=v"(r) : "v"(a), "v"(b)); return r;
}

// Stage one t-row chunk: issue ALL loads, then ALL ds_writes (ds addr saved in
// regs -- no addr recompute). rr/ds are transient, dead before compute.
#define STAGE(NT, CE_, NIT, T0)                                            \
    {                                                                      \
        f2 rr[NIT]; int dsa[NIT];                                          \
        _Pragma("unroll")                                                  \
        for (int i = 0; i < NIT; ++i) {                                    \
            const int e = lane + i * 64;                                   \
            f2 v = (f2){0.f, 0.f};                                         \
            int da = 0;                                                    \
            if (e < (CE_)) {                                               \
                const int gq = e / ((NT) * NW), rq = e - gq * ((NT) * NW); \
                const int tq = rq / NW, wq = rq - tq * NW;                 \
                const int Mq = Mw + gq;                                    \
                da = gq * BUFS + wq * (NT) + tq;                           \
                if (Mq < NM) {                                             \
                    const int nq = Mq >> 4, aq = Mq & 15;                  \
                    const int go = (nq * NS + (T0) + tq) * (NA * NW) + aq * NW + wq; \
                    v = (f2){x_real[go], x_imag[go]};                      \
                }                                                          \
            }                                                              \
            rr[i] = v; dsa[i] = da;                                        \
        }                                                                  \
        _Pragma("unroll")                                                  \
        for (int i = 0; i < NIT; ++i) {                                    \
            const int e = lane + i * 64;                                   \
            if (e < (CE_)) wbuf[dsa[i]] = rr[i];                           \
        }                                                                  \
    }

// Paired A+B over full rows for NT t's starting at TBASE, chunk layout
// bp[w*NT + t]. w=0 initializes V (F[0][c] = 1/sqrt(33) real -> pk_mul).
#define COMPUTE_CHUNK(NT, TBASE)                                           \
    if (act) {                                                             \
        const f2* bp = wbuf + gg * BUFS;                                   \
        {   /* w = 0: V init */                                            \
            f2 fv[CPT];                                                    \
            _Pragma("unroll")                                              \
            for (int k = 0; k < CPT; ++k) fv[k] = sFsub[c0 + k];           \
            _Pragma("unroll")                                              \
            for (int t = 0; t < (NT); ++t) {                               \
                const f2 xc = bp[t];                                       \
                _Pragma("unroll")                                          \
                for (int k = 0; k < CPT; ++k)                              \
                    V[(TBASE) + t][k] = pkmul_re(xc, fv[k]);               \
            }                                                              \
        }                                                                  \
        _Pragma("unroll 4")                                                \
        for (int wp = 1; wp <= 16; ++wp) {                                 \
            const int wq = NW - wp;                                        \
            f2 xcA[NT], xcB[NT];                                           \
            _Pragma("unroll")                                              \
            for (int t = 0; t < (NT); ++t) xcA[t] = bp[wp * (NT) + t];     \
            _Pragma("unroll")                                              \
            for (int t = 0; t < (NT); ++t) xcB[t] = bp[wq * (NT) + t];     \
            f2 fv[CPT];                                                    \
            _Pragma("unroll")                                              \
            for (int k = 0; k < CPT; ++k) fv[k] = sFsub[wp * NW + c0 + k]; \
            _Pragma("unroll")                                              \
            for (int t = 0; t < (NT); ++t) {                               \
                const f2 u = pkadd(xcA[t], xcB[t]);                        \
                const f2 d = pksub(xcA[t], xcB[t]);                        \
                _Pragma("unroll")                                          \
                for (int k = 0; k < CPT; ++k) {                            \
                    cmac_re(V[(TBASE) + t][k], u, fv[k]);                  \
                    cmac_im(V[(TBASE) + t][k], d, fv[k]);                  \
                }                                                          \
            }                                                              \
        }                                                                  \
    }

__global__ __launch_bounds__(THREADS, 6) void autocorr_kernel(
    const float* __restrict__ x_real, const float* __restrict__ x_imag,
    const float* __restrict__ Fsym_re, const float* __restrict__ Fsym_im,
    const float* __restrict__ Fsub_re, const float* __restrict__ Fsub_im,
    float* __restrict__ out, int NM, int write_complex)
{
    __shared__ f2 sFsym[NS * NS];     // [s][t]
    __shared__ f2 sFsub[NW * NW];     // [w][v] row-major (symmetric)
    __shared__ f2 buf[GM * BUFS];     // per-matrix 99: x rows chunk, then T2

    const int tid = threadIdx.x;
    const int wave = tid >> 6;
    const int lane = tid & 63;
    const int Mw = blockIdx.x * GM + wave * MPW;
    f2* const wbuf = &buf[wave * MPW * BUFS];

    // ---- F staging (cooperative) ----
    for (int i = tid; i < NW * NW; i += THREADS)
        sFsub[i] = (f2){Fsub_re[i], Fsub_im[i]};
    if (tid < NS * NS) sFsym[tid] = (f2){Fsym_re[tid], Fsym_im[tid]};

    // ---- chunk0 (t=0..2): global->reg->LDS, latency overlaps F staging ----
    STAGE(C0T, C0E, IT0, 0);
    __syncthreads();   // the ONLY barrier

    const int g = lane / TPM;                 // 0..4 active, 5 for idle lanes
    const int j = lane - g * TPM;
    const bool act = (lane < MPW * TPM);      // 55 of 64 lanes compute
    const int gg = act ? g : 0;
    const int M = Mw + gg;
    const int c0 = 3 * j;

    f2 V[NS][CPT];   // initialized inside COMPUTE_CHUNK's w=0 block (act lanes)

    COMPUTE_CHUNK(C0T, 0);

    // ---- chunk1 (t=3,4): staged now; 24-wave TLP covers the latency.
    //      Overwrites chunk0's region: safe per-wave in-order DS. ----
    STAGE(C1T, C1E, IT1, C0T);
    asm volatile("s_waitcnt lgkmcnt(0)" ::: "memory");

    COMPUTE_CHUNK(C1T, C0T);

    // ---- Stage C/D: X = F_sym*V (paired); P = |X|^2; T2 (Hermitian p<3) ----
    f2 T2[3][CPT];
#pragma unroll
    for (int p = 0; p < 3; ++p)
#pragma unroll
        for (int k = 0; k < CPT; ++k) T2[p][k] = (f2){0.f, 0.f};
    if (act) {
        // In-place pairing transform: Fsym[s][4]=conj(Fsym[s][1]),
        // Fsym[s][3]=conj(Fsym[s][2]):  V1<-V1+V4, V4<-V1-V4, V2<-V2+V3, V3<-V2-V3
#pragma unroll
        for (int k = 0; k < CPT; ++k) {
            f2 a = V[1][k], b = V[4][k];
            V[1][k] = pkadd(a, b); V[4][k] = pksub(a, b);
            a = V[2][k]; b = V[3][k];
            V[2][k] = pkadd(a, b); V[3][k] = pksub(a, b);
        }
#pragma unroll
        for (int s = 0; s < NS; ++s) {
            const f2 f0 = sFsym[s * NS + 0];   // = 1/sqrt(5), real
            const f2 f1 = sFsym[s * NS + 1];
            const f2 fc2 = sFsym[s * NS + 2];
            f2 X[CPT];
#pragma unroll
            for (int k = 0; k < CPT; ++k) {
                X[k] = pkmul_re(V[0][k], f0);
                cmac_re(X[k], V[1][k], f1); cmac_im(X[k], V[4][k], f1);
                cmac_re(X[k], V[2][k], fc2); cmac_im(X[k], V[3][k], fc2);
            }
#pragma unroll
            for (int k = 0; k < CPT; ++k) {
                const float Pv = X[k].x * X[k].x + X[k].y * X[k].y;
                const f2 Pp = (f2){Pv, Pv};
#pragma unroll
                for (int p = 0; p < 3; ++p)
                    cmacr(T2[p][k], sFsym[s * NS + p], Pp);
            }
        }
        // T2 col-major into the same wave-private region (after all x reads).
        f2* const wb = wbuf + gg * BUFS;
#pragma unroll
        for (int k = 0; k < CPT; ++k)
#pragma unroll
            for (int p = 0; p < 3; ++p)
                wb[(c0 + k) * 3 + p] = T2[p][k];
    }
    asm volatile("s_waitcnt lgkmcnt(0)" ::: "memory");

    // ---- Stage E: Y[p][q] = sum_v T2[p][v]*conj(Fsub[q][v]), q = c0+k ----
    if (act) {
        const f2* bp = wbuf + gg * BUFS;
        if (!write_complex) {
            // Paired real path: v & 33-v give  su*fr + sd*fi  with
            // su = tcA.x+tcB.x, sd = tcA.y-tcB.y; fold .x+.y at the end.
            f2 Ypk[3][CPT];
            {   // v = 0: F[q][0] = 1/sqrt(33) real -> pk_mul init
                f2 fw[CPT];
#pragma unroll
                for (int k = 0; k < CPT; ++k) fw[k] = sFsub[(c0 + k) * NW];
#pragma unroll
                for (int p = 0; p < 3; ++p) {
                    const f2 tc = bp[p];
#pragma unroll
                    for (int k = 0; k < CPT; ++k)
                        Ypk[p][k] = pkmul(tc, fw[k]);
                }
            }
#pragma unroll 4
            for (int vp = 1; vp <= 16; ++vp) {
                const int vq = NW - vp;
                f2 tcA[3], tcB[3];
#pragma unroll
                for (int p = 0; p < 3; ++p) tcA[p] = bp[vp * 3 + p];
#pragma unroll
                for (int p = 0; p < 3; ++p) tcB[p] = bp[vq * 3 + p];
                f2 e2[3];
#pragma unroll
                for (int p = 0; p < 3; ++p) e2[p] = pkaddsub(tcA[p], tcB[p]);
                f2 fw[CPT];
#pragma unroll
                for (int k = 0; k < CPT; ++k) fw[k] = sFsub[(c0 + k) * NW + vp];
#pragma unroll
                for (int p = 0; p < 3; ++p)
#pragma unroll
                    for (int k = 0; k < CPT; ++k)
                        pkfma(Ypk[p][k], e2[p], fw[k]);
            }
            if (M < NM) {
                const int n = M >> 4, a = M & 15;
                const int obase = ((n * NS) * NA + a) * NW;
#pragma unroll
                for (int p = 0; p < 3; ++p) {
                    const int pp = (NS - p) % NS;   // 0,4,3
#pragma unroll
                    for (int k = 0; k < CPT; ++k) {
                        const int q = c0 + k;
                        const int qq = (NW - q) % NW;
                        const float Yr = Ypk[p][k].x + Ypk[p][k].y;
                        out[obase + p * (NA * NW) + q] = Yr;
                        out[obase + pp * (NA * NW) + qq] = Yr;
                    }
                }
            }
        } else {
            // Fallback: full complex output (not expected on this harness).
            f2 Y[3][CPT];
#pragma unroll
            for (int p = 0; p < 3; ++p)
#pragma unroll
                for (int k = 0; k < CPT; ++k) Y[p][k] = (f2){0.f, 0.f};
            for (int v = 0; v < NW; ++v) {
                f2 tc[3];
#pragma unroll
                for (int p = 0; p < 3; ++p) tc[p] = bp[v * 3 + p];
                f2 fw[CPT];
#pragma unroll
                for (int k = 0; k < CPT; ++k) fw[k] = sFsub[(c0 + k) * NW + v];
#pragma unroll
                for (int p = 0; p < 3; ++p)
#pragma unroll
                    for (int k = 0; k < CPT; ++k) {
                        Y[p][k].x = fmaf(tc[p].x, fw[k].x, Y[p][k].x);
                        Y[p][k].x = fmaf(tc[p].y, fw[k].y, Y[p][k].x);
                        Y[p][k].y = fmaf(tc[p].y, fw[k].x, Y[p][k].y);
                        Y[p][k].y = fmaf(-tc[p].x, fw[k].y, Y[p][k].y);
                    }
            }
            if (M < NM) {
                const int n = M >> 4, a = M & 15;
#pragma unroll
                for (int p = 0; p < 3; ++p) {
                    const int pp = (NS - p) % NS;
#pragma unroll
                    for (int k = 0; k < CPT; ++k) {
                        const int q = c0 + k;
                        const int qq = (NW - q) % NW;
                        ((float2*)out)[((n * NS + p) * NA + a) * NW + q] =
                            make_float2(Y[p][k].x, Y[p][k].y);
                        ((float2*)out)[((n * NS + pp) * NA + a) * NW + qq] =
                            make_float2(Y[p][k].x, -Y[p][k].y);
                    }
                }
            }
        }
    }
}

extern "C" void kernel_launch(void* const* d_in, const int* in_sizes, int n_in,
                              void* d_out, int out_size, void* d_ws, size_t ws_size,
                              hipStream_t stream) {
    const float* x_real  = (const float*)d_in[0];
    const float* x_imag  = (const float*)d_in[1];
    const float* Fsym_re = (const float*)d_in[2];
    const float* Fsym_im = (const float*)d_in[3];
    const float* Fsub_re = (const float*)d_in[4];
    const float* Fsub_im = (const float*)d_in[5];

    const int NM = in_sizes[0] / SW;
    const long long n_cplx = (long long)in_sizes[0];
    const int write_complex = ((long long)out_size >= 2 * n_cplx) ? 1 : 0;

    const int blocks = (NM + GM - 1) / GM;

    autocorr_kernel<<<blocks, THREADS, 0, stream>>>(
        x_real, x_imag, Fsym_re, Fsym_im, Fsub_re, Fsub_im,
        (float*)d_out, NM, write_complex);
}

// Round 8
// 164.280 us; speedup vs baseline: 1.1637x; 1.0687x over previous
//
#include <hip/hip_runtime.h>

#define NS 5      // symbols
#define NW 33     // subcarriers
#define NA 16     // antennas
#define SW 165    // NS*NW
#define BUFS 99   // per-matrix LDS buffer (f2): x rows chunk (<=99), then T2 (99)
#define MPW 5     // matrices per wave
#define GM 20     // matrices per block
#define TPM 11    // threads per matrix
#define CPT 3     // columns per thread
#define THREADS 256

// t-row chunks: chunk0 = t{0,1,2} full rows, chunk1 = t{3,4} full rows.
#define C0T 3
#define C0E (C0T*NW*MPW)   // 495
#define IT0 8
#define C1T 2
#define C1E (C1T*NW*MPW)   // 330
#define IT1 6

// R17: un-spill R16. R16's conj-pair math cut VALU-busy 53->34us but its live
// set overflowed launch_bounds(256,6)'s ~80-VGPR cap -> 17MB scratch WRITE and
// +20us stall. Fix: (256,5) gives ~100 VGPR (peak live ~74 fits). Headroom
// also restores the chunk1 reg-prefetch (12 transient regs, dead before the
// C/D peak): chunk1 loads issue before chunk0's ~2800cy compute, killing the
// exposed global-latency gap. Kept: conj-pair FLOP cut (R16), 99-f2 LDS
// layout (R13), pk_fma (R11), wave-autonomy (R10), LDS staging (R12 lesson).
typedef float f2 __attribute__((ext_vector_type(2)));

// z += u * Re(f):  (z.x += u.x*f.lo, z.y += u.y*f.lo)
__device__ __forceinline__ void cmac_re(f2& z, f2 u, f2 f) {
    asm("v_pk_fma_f32 %0, %1, %2, %0 op_sel:[0,0,0] op_sel_hi:[1,0,1]"
        : "+v"(z) : "v"(u), "v"(f));
}
// z += i * d * Im(f):  (z.x += -d.y*f.hi, z.y += d.x*f.hi)
__device__ __forceinline__ void cmac_im(f2& z, f2 d, f2 f) {
    asm("v_pk_fma_f32 %0, %1, %2, %0 op_sel:[1,1,0] op_sel_hi:[0,1,1] neg_lo:[1,0,0]"
        : "+v"(z) : "v"(d), "v"(f));
}
// z += conj(f) * P, P real pair Pp=(P,P): lo zr+=f.x*P, hi zi+=-f.y*P
__device__ __forceinline__ void cmacr(f2& z, f2 f, f2 Pp) {
    asm("v_pk_fma_f32 %0, %1, %2, %0 op_sel:[0,0,0] op_sel_hi:[1,1,1] neg_hi:[1,0,0]"
        : "+v"(z) : "v"(f), "v"(Pp));
}
// plain packed: z += a*b elementwise
__device__ __forceinline__ void pkfma(f2& z, f2 a, f2 b) {
    asm("v_pk_fma_f32 %0, %1, %2, %0 op_sel:[0,0,0] op_sel_hi:[1,1,1]"
        : "+v"(z) : "v"(a), "v"(b));
}
// r = a + b (packed)
__device__ __forceinline__ f2 pkadd(f2 a, f2 b) {
    f2 r; asm("v_pk_add_f32 %0, %1, %2" : "=v"(r) : "v"(a), "v"(b)); return r;
}
// r = a - b (packed)
__device__ __forceinline__ f2 pksub(f2 a, f2 b) {
    f2 r; asm("v_pk_add_f32 %0, %1, %2 neg_lo:[0,1] neg_hi:[0,1]"
              : "=v"(r) : "v"(a), "v"(b)); return r;
}
// r = (a.x + b.x, a.y - b.y)
__device__ __forceinline__ f2 pkaddsub(f2 a, f2 b) {
    f2 r; asm("v_pk_add_f32 %0, %1, %2 neg_hi:[0,1]"
              : "=v"(r) : "v"(a), "v"(b)); return r;
}
// r = u * Re(f) broadcast: (u.x*f.lo, u.y*f.lo)  -- accumulator init
__device__ __forceinline__ f2 pkmul_re(f2 u, f2 f) {
    f2 r; asm("v_pk_mul_f32 %0, %1, %2 op_sel:[0,0] op_sel_hi:[1,0]"
              : "=v"(r) : "v"(u), "v"(f)); return r;
}
// r = a * b elementwise -- accumulator init
__device__ __forceinline__ f2 pkmul(f2 a, f2 b) {
    f2 r; asm("v_pk_mul_f32 %0, %1, %2" : "=v"(r) : "v"(a), "v"(b)); return r;
}

// Issue all global loads for one t-row chunk into regs R[], ds addrs into DS[].
#define STAGE_LOAD(R, DS, NT, CE_, NIT, T0)                                \
    _Pragma("unroll")                                                      \
    for (int i = 0; i < NIT; ++i) {                                        \
        const int e = lane + i * 64;                                       \
        f2 v = (f2){0.f, 0.f};                                             \
        int da = 0;                                                        \
        if (e < (CE_)) {                                                   \
            const int gq = e / ((NT) * NW), rq = e - gq * ((NT) * NW);     \
            const int tq = rq / NW, wq = rq - tq * NW;                     \
            const int Mq = Mw + gq;                                        \
            da = gq * BUFS + wq * (NT) + tq;                               \
            if (Mq < NM) {                                                 \
                const int nq = Mq >> 4, aq = Mq & 15;                      \
                const int go = (nq * NS + (T0) + tq) * (NA * NW) + aq * NW + wq; \
                v = (f2){x_real[go], x_imag[go]};                          \
            }                                                              \
        }                                                                  \
        R[i] = v; DS[i] = da;                                              \
    }

// Write a register-staged chunk to the wave-private LDS region.
#define STAGE_WRITE(R, DS, CE_, NIT)                                       \
    _Pragma("unroll")                                                      \
    for (int i = 0; i < NIT; ++i) {                                        \
        const int e = lane + i * 64;                                       \
        if (e < (CE_)) wbuf[DS[i]] = R[i];                                 \
    }

// Paired A+B over full rows for NT t's starting at TBASE, chunk layout
// bp[w*NT + t]. w=0 initializes V (F[0][c] = 1/sqrt(33) real -> pk_mul).
#define COMPUTE_CHUNK(NT, TBASE)                                           \
    if (act) {                                                             \
        const f2* bp = wbuf + gg * BUFS;                                   \
        {   /* w = 0: V init */                                            \
            f2 fv[CPT];                                                    \
            _Pragma("unroll")                                              \
            for (int k = 0; k < CPT; ++k) fv[k] = sFsub[c0 + k];           \
            _Pragma("unroll")                                              \
            for (int t = 0; t < (NT); ++t) {                               \
                const f2 xc = bp[t];                                       \
                _Pragma("unroll")                                          \
                for (int k = 0; k < CPT; ++k)                              \
                    V[(TBASE) + t][k] = pkmul_re(xc, fv[k]);               \
            }                                                              \
        }                                                                  \
        _Pragma("unroll 4")                                                \
        for (int wp = 1; wp <= 16; ++wp) {                                 \
            const int wq = NW - wp;                                        \
            f2 xcA[NT], xcB[NT];                                           \
            _Pragma("unroll")                                              \
            for (int t = 0; t < (NT); ++t) xcA[t] = bp[wp * (NT) + t];     \
            _Pragma("unroll")                                              \
            for (int t = 0; t < (NT); ++t) xcB[t] = bp[wq * (NT) + t];     \
            f2 fv[CPT];                                                    \
            _Pragma("unroll")                                              \
            for (int k = 0; k < CPT; ++k) fv[k] = sFsub[wp * NW + c0 + k]; \
            _Pragma("unroll")                                              \
            for (int t = 0; t < (NT); ++t) {                               \
                const f2 u = pkadd(xcA[t], xcB[t]);                        \
                const f2 d = pksub(xcA[t], xcB[t]);                        \
                _Pragma("unroll")                                          \
                for (int k = 0; k < CPT; ++k) {                            \
                    cmac_re(V[(TBASE) + t][k], u, fv[k]);                  \
                    cmac_im(V[(TBASE) + t][k], d, fv[k]);                  \
                }                                                          \
            }                                                              \
        }                                                                  \
    }

__global__ __launch_bounds__(THREADS, 5) void autocorr_kernel(
    const float* __restrict__ x_real, const float* __restrict__ x_imag,
    const float* __restrict__ Fsym_re, const float* __restrict__ Fsym_im,
    const float* __restrict__ Fsub_re, const float* __restrict__ Fsub_im,
    float* __restrict__ out, int NM, int write_complex)
{
    __shared__ f2 sFsym[NS * NS];     // [s][t]
    __shared__ f2 sFsub[NW * NW];     // [w][v] row-major (symmetric)
    __shared__ f2 buf[GM * BUFS];     // per-matrix 99: x rows chunk, then T2

    const int tid = threadIdx.x;
    const int wave = tid >> 6;
    const int lane = tid & 63;
    const int Mw = blockIdx.x * GM + wave * MPW;
    f2* const wbuf = &buf[wave * MPW * BUFS];

    // ---- F staging (cooperative) ----
    for (int i = tid; i < NW * NW; i += THREADS)
        sFsub[i] = (f2){Fsub_re[i], Fsub_im[i]};
    if (tid < NS * NS) sFsym[tid] = (f2){Fsym_re[tid], Fsym_im[tid]};

    // ---- chunk0 (t=0..2): global->reg->LDS, latency overlaps F staging ----
    {
        f2 rr0[IT0]; int ds0[IT0];
        STAGE_LOAD(rr0, ds0, C0T, C0E, IT0, 0);
        STAGE_WRITE(rr0, ds0, C0E, IT0);
    }
    __syncthreads();   // the ONLY barrier

    // ---- chunk1 (t=3,4) loads issue NOW: latency hides under chunk0 compute.
    //      12 regs + 6 addr, all dead before the stage-C/D register peak. ----
    f2 rr1[IT1]; int ds1[IT1];
    STAGE_LOAD(rr1, ds1, C1T, C1E, IT1, C0T);

    const int g = lane / TPM;                 // 0..4 active, 5 for idle lanes
    const int j = lane - g * TPM;
    const bool act = (lane < MPW * TPM);      // 55 of 64 lanes compute
    const int gg = act ? g : 0;
    const int M = Mw + gg;
    const int c0 = 3 * j;

    f2 V[NS][CPT];   // initialized inside COMPUTE_CHUNK's w=0 block (act lanes)

    COMPUTE_CHUNK(C0T, 0);

    // ---- chunk1 reg->LDS (overwrites chunk0's region: safe per-wave
    //      in-order DS; compiler inserts the vmcnt for rr1) ----
    STAGE_WRITE(rr1, ds1, C1E, IT1);
    asm volatile("s_waitcnt lgkmcnt(0)" ::: "memory");

    COMPUTE_CHUNK(C1T, C0T);

    // ---- Stage C/D: X = F_sym*V (paired); P = |X|^2; T2 (Hermitian p<3) ----
    f2 T2[3][CPT];
#pragma unroll
    for (int p = 0; p < 3; ++p)
#pragma unroll
        for (int k = 0; k < CPT; ++k) T2[p][k] = (f2){0.f, 0.f};
    if (act) {
        // In-place pairing transform: Fsym[s][4]=conj(Fsym[s][1]),
        // Fsym[s][3]=conj(Fsym[s][2]):  V1<-V1+V4, V4<-V1-V4, V2<-V2+V3, V3<-V2-V3
#pragma unroll
        for (int k = 0; k < CPT; ++k) {
            f2 a = V[1][k], b = V[4][k];
            V[1][k] = pkadd(a, b); V[4][k] = pksub(a, b);
            a = V[2][k]; b = V[3][k];
            V[2][k] = pkadd(a, b); V[3][k] = pksub(a, b);
        }
#pragma unroll
        for (int s = 0; s < NS; ++s) {
            const f2 f0 = sFsym[s * NS + 0];   // = 1/sqrt(5), real
            const f2 f1 = sFsym[s * NS + 1];
            const f2 fc2 = sFsym[s * NS + 2];
            f2 X[CPT];
#pragma unroll
            for (int k = 0; k < CPT; ++k) {
                X[k] = pkmul_re(V[0][k], f0);
                cmac_re(X[k], V[1][k], f1); cmac_im(X[k], V[4][k], f1);
                cmac_re(X[k], V[2][k], fc2); cmac_im(X[k], V[3][k], fc2);
            }
#pragma unroll
            for (int k = 0; k < CPT; ++k) {
                const float Pv = X[k].x * X[k].x + X[k].y * X[k].y;
                const f2 Pp = (f2){Pv, Pv};
#pragma unroll
                for (int p = 0; p < 3; ++p)
                    cmacr(T2[p][k], sFsym[s * NS + p], Pp);
            }
        }
        // T2 col-major into the same wave-private region (after all x reads).
        f2* const wb = wbuf + gg * BUFS;
#pragma unroll
        for (int k = 0; k < CPT; ++k)
#pragma unroll
            for (int p = 0; p < 3; ++p)
                wb[(c0 + k) * 3 + p] = T2[p][k];
    }
    asm volatile("s_waitcnt lgkmcnt(0)" ::: "memory");

    // ---- Stage E: Y[p][q] = sum_v T2[p][v]*conj(Fsub[q][v]), q = c0+k ----
    if (act) {
        const f2* bp = wbuf + gg * BUFS;
        if (!write_complex) {
            // Paired real path: v & 33-v give  su*fr + sd*fi  with
            // su = tcA.x+tcB.x, sd = tcA.y-tcB.y; fold .x+.y at the end.
            f2 Ypk[3][CPT];
            {   // v = 0: F[q][0] = 1/sqrt(33) real -> pk_mul init
                f2 fw[CPT];
#pragma unroll
                for (int k = 0; k < CPT; ++k) fw[k] = sFsub[(c0 + k) * NW];
#pragma unroll
                for (int p = 0; p < 3; ++p) {
                    const f2 tc = bp[p];
#pragma unroll
                    for (int k = 0; k < CPT; ++k)
                        Ypk[p][k] = pkmul(tc, fw[k]);
                }
            }
#pragma unroll 4
            for (int vp = 1; vp <= 16; ++vp) {
                const int vq = NW - vp;
                f2 e2[3];   // built in place: e2 = pkaddsub(A, B)
#pragma unroll
                for (int p = 0; p < 3; ++p) {
                    const f2 ta = bp[vp * 3 + p];
                    const f2 tb = bp[vq * 3 + p];
                    e2[p] = pkaddsub(ta, tb);
                }
                f2 fw[CPT];
#pragma unroll
                for (int k = 0; k < CPT; ++k) fw[k] = sFsub[(c0 + k) * NW + vp];
#pragma unroll
                for (int p = 0; p < 3; ++p)
#pragma unroll
                    for (int k = 0; k < CPT; ++k)
                        pkfma(Ypk[p][k], e2[p], fw[k]);
            }
            if (M < NM) {
                const int n = M >> 4, a = M & 15;
                const int obase = ((n * NS) * NA + a) * NW;
#pragma unroll
                for (int p = 0; p < 3; ++p) {
                    const int pp = (NS - p) % NS;   // 0,4,3
#pragma unroll
                    for (int k = 0; k < CPT; ++k) {
                        const int q = c0 + k;
                        const int qq = (NW - q) % NW;
                        const float Yr = Ypk[p][k].x + Ypk[p][k].y;
                        out[obase + p * (NA * NW) + q] = Yr;
                        out[obase + pp * (NA * NW) + qq] = Yr;
                    }
                }
            }
        } else {
            // Fallback: full complex output (not expected on this harness).
            f2 Y[3][CPT];
#pragma unroll
            for (int p = 0; p < 3; ++p)
#pragma unroll
                for (int k = 0; k < CPT; ++k) Y[p][k] = (f2){0.f, 0.f};
            for (int v = 0; v < NW; ++v) {
                f2 tc[3];
#pragma unroll
                for (int p = 0; p < 3; ++p) tc[p] = bp[v * 3 + p];
                f2 fw[CPT];
#pragma unroll
                for (int k = 0; k < CPT; ++k) fw[k] = sFsub[(c0 + k) * NW + v];
#pragma unroll
                for (int p = 0; p < 3; ++p)
#pragma unroll
                    for (int k = 0; k < CPT; ++k) {
                        Y[p][k].x = fmaf(tc[p].x, fw[k].x, Y[p][k].x);
                        Y[p][k].x = fmaf(tc[p].y, fw[k].y, Y[p][k].x);
                        Y[p][k].y = fmaf(tc[p].y, fw[k].x, Y[p][k].y);
                        Y[p][k].y = fmaf(-tc[p].x, fw[k].y, Y[p][k].y);
                    }
            }
            if (M < NM) {
                const int n = M >> 4, a = M & 15;
#pragma unroll
                for (int p = 0; p < 3; ++p) {
                    const int pp = (NS - p) % NS;
#pragma unroll
                    for (int k = 0; k < CPT; ++k) {
                        const int q = c0 + k;
                        const int qq = (NW - q) % NW;
                        ((float2*)out)[((n * NS + p) * NA + a) * NW + q] =
                            make_float2(Y[p][k].x, Y[p][k].y);
                        ((float2*)out)[((n * NS + pp) * NA + a) * NW + qq] =
                            make_float2(Y[p][k].x, -Y[p][k].y);
                    }
                }
            }
        }
    }
}

extern "C" void kernel_launch(void* const* d_in, const int* in_sizes, int n_in,
                              void* d_out, int out_size, void* d_ws, size_t ws_size,
                              hipStream_t stream) {
    const float* x_real  = (const float*)d_in[0];
    const float* x_imag  = (const float*)d_in[1];
    const float* Fsym_re = (const float*)d_in[2];
    const float* Fsym_im = (const float*)d_in[3];
    const float* Fsub_re = (const float*)d_in[4];
    const float* Fsub_im = (const float*)d_in[5];

    const int NM = in_sizes[0] / SW;
    const long long n_cplx = (long long)in_sizes[0];
    const int write_complex = ((long long)out_size >= 2 * n_cplx) ? 1 : 0;

    const int blocks = (NM + GM - 1) / GM;

    autocorr_kernel<<<blocks, THREADS, 0, stream>>>(
        x_real, x_imag, Fsym_re, Fsym_im, Fsub_re, Fsub_im,
        (float*)d_out, NM, write_complex);
}